// Round 8
// baseline (358.184 us; speedup 1.0000x reference)
//
#include <hip/hip_runtime.h>
#include <hip/hip_cooperative_groups.h>
#include <cmath>

namespace cg = cooperative_groups;

static constexpr int kC = 1024;
static constexpr int kD = 768;
static constexpr int kThreads = 256;
static constexpr float kTauInv = 10.0f;
static constexpr int kKS = kD / 32;       // 24 K-steps
static constexpr int kMaxPos = 128;       // per-batch anchor capacity (actual ~51)
static constexpr int kMT = kMaxPos / 16;  // 8 M-tiles per batch

typedef __attribute__((ext_vector_type(8))) short short8_t;
typedef __attribute__((ext_vector_type(4))) float f32x4_t;
union I4S8 { int4 i; short8_t s; };

__device__ __forceinline__ unsigned fkey(float f) {
  unsigned b = __float_as_uint(f);
  return (b & 0x80000000u) ? ~b : (b | 0x80000000u);
}

// round-to-nearest-even fp32 -> bf16 bits
__device__ __forceinline__ unsigned bfr(float x) {
  unsigned u = __float_as_uint(x);
  return (u + 0x7fffu + ((u >> 16) & 1u)) >> 16;
}

// wave-uniform count of a 16-element-per-lane predicate set via ballot+popcount
#define BALLOT_COUNT16(expr, dst)                       \
  {                                                     \
    int c__ = 0;                                        \
    _Pragma("unroll")                                   \
    for (int j = 0; j < 16; ++j)                        \
      c__ += (int)__popcll(__ballot(expr));             \
    dst = c__;                                          \
  }

// ---- single cooperative kernel: prep -> grid.sync -> GEMM -> grid.sync -> epilogue ----
// LDS: afrag 24576 B (phase-1 rand aliases its first 4 KB as keys) -> ~25 KB/block
// => 2 blocks/CU co-resident (512 blocks on 256 CUs) with __launch_bounds__(256,2).
__global__ void __launch_bounds__(kThreads, 2) mono_kernel(
    const float* __restrict__ f, const float* __restrict__ proto,
    const int* __restrict__ targets, const float* __restrict__ rs,
    int4* __restrict__ pnf, int* __restrict__ flags, int* __restrict__ cnt,
    float* __restrict__ poscnt, int* __restrict__ alist,
    float* __restrict__ simsg, float* __restrict__ out,
    int B, int K_hard, int K_rand) {
  cg::grid_group grid = cg::this_grid();
  __shared__ __align__(16) int4 afrag[kKS * 64];   // 24576 B
  __shared__ float scl16[16];
  __shared__ int rowc[16];

  int blk = blockIdx.x;
  int t = threadIdx.x;
  int wq = t >> 6, ln = t & 63;

  // ================= phase 1: prep =================
  if (blk == 0 && t == 0) *out = 0.f;

  if (blk < 64) {
    // ---- pack prototypes rows n0..n0+15 -> pnf (bf16, MFMA B layout) ----
    int n0 = blk * 16;
    {
      int r = t >> 4, part = t & 15;
      const float4* row4 = (const float4*)(proto + (size_t)(n0 + r) * kD) + part * 12;
      float ss = 0.f;
      #pragma unroll
      for (int i = 0; i < 12; ++i) {
        float4 v = row4[i];
        ss += v.x * v.x + v.y * v.y + v.z * v.z + v.w * v.w;
      }
      #pragma unroll
      for (int off = 8; off > 0; off >>= 1) ss += __shfl_xor(ss, off, 16);
      if (part == 0) scl16[r] = 1.0f / fmaxf(sqrtf(ss), 1e-12f);
    }
    __syncthreads();
    #pragma unroll
    for (int i = 0; i < 6; ++i) {
      int chunk = i * 256 + t;
      int ks = chunk >> 6;
      int cl = chunk & 63;
      int col = cl & 15;
      int k0 = ks * 32 + (cl >> 4) * 8;
      const float* src = proto + (size_t)(n0 + col) * kD + k0;  // L1-warm from norm pass
      float s = scl16[col];
      float4 a = *(const float4*)(src);
      float4 b = *(const float4*)(src + 4);
      int4 pk;
      pk.x = bfr(a.x * s) | (bfr(a.y * s) << 16);
      pk.y = bfr(a.z * s) | (bfr(a.w * s) << 16);
      pk.z = bfr(b.x * s) | (bfr(b.y * s) << 16);
      pk.w = bfr(b.z * s) | (bfr(b.w * s) << 16);
      pnf[(size_t)((blk * kKS + ks) << 6) + cl] = pk;
    }
  } else if (blk < 80) {
    // ---- rand select for batch b ----
    unsigned* keys = (unsigned*)afrag;   // alias (4 KB of 24 KB)
    int b = blk - 64;
    #pragma unroll
    for (int k = 0; k < 4; ++k) {
      int e = t + 256 * k;
      int tg = targets[b * kC + e];
      float v = (tg == 0) ? rs[b * kC + e] : -INFINITY;
      keys[e] = fkey(v);  // positives -> fkey(-inf) < 0x80000000 <= fkey(rs>=0)
    }
    __syncthreads();
    unsigned mk[16];
    #pragma unroll
    for (int j = 0; j < 16; ++j) mk[j] = keys[ln + 64 * j];

    unsigned lo = 0u, hi = 0xFFFFFFFFu;
    while (lo < hi) {
      unsigned mid = lo + ((hi - lo) >> 1);
      int c_;
      BALLOT_COUNT16(mk[j] > mid, c_);
      if (c_ >= K_rand) lo = mid + 1u; else hi = mid;
    }
    unsigned thr = lo;

    int n_g, n_eq, cp;
    BALLOT_COUNT16(mk[j] > thr, n_g);
    BALLOT_COUNT16(mk[j] == thr, n_eq);
    BALLOT_COUNT16(mk[j] < 0x80000000u, cp);
    int need = K_rand - n_g;
    bool take_all_eq = (n_eq <= need);

    if (t == 0) {
      poscnt[b] = fmaxf((float)cp, 1.f);
      cnt[b] = (cp < kMaxPos) ? cp : kMaxPos;
    }

    if (wq == 0) {
      int pref = 0;
      #pragma unroll
      for (int j = 0; j < 16; ++j) {
        unsigned long long ball = __ballot(mk[j] < 0x80000000u);
        if (mk[j] < 0x80000000u) {
          int rank = pref + __popcll(ball & ((1ull << ln) - 1ull));
          if (rank < kMaxPos) alist[b * kMaxPos + rank] = ln + 64 * j;
        }
        pref += __popcll(ball);
      }
    }

    if (take_all_eq) {
      #pragma unroll
      for (int k = 0; k < 4; ++k) {
        int j = wq + 4 * k;
        int e = ln + 64 * j;  // == t + 256*k
        unsigned kk = mk[j];
        int sel = (kk >= thr && kk >= 0x80000000u) ? 1 : 0;
        int pos = (kk < 0x80000000u) ? 2 : 0;
        flags[b * kC + e] = sel | pos;
      }
    } else {
      int pref = 0;
      int rankj[16];
      #pragma unroll
      for (int j = 0; j < 16; ++j) {
        unsigned long long ball = __ballot(mk[j] == thr);
        rankj[j] = pref + __popcll(ball & ((1ull << ln) - 1ull));
        pref += __popcll(ball);
      }
      #pragma unroll
      for (int k = 0; k < 4; ++k) {
        int j = wq + 4 * k;
        int e = ln + 64 * j;
        unsigned kk = mk[j];
        int sel = (kk > thr) ? 1 : ((kk == thr && rankj[j] < need) ? 1 : 0);
        int pos = (kk < 0x80000000u) ? 2 : 0;
        flags[b * kC + e] = sel | pos;
      }
    }
  }

  __threadfence();
  grid.sync();

  // ================= phase 2: GEMM (b, mt, nb) = 16 x 8 x 4 =================
  {
    int b = blk >> 5;
    int mt = (blk >> 2) & 7;
    int nb = blk & 3;
    int cb = cnt[b];
    if (mt * 16 < cb) {
      if (t < 16) {
        int idx = mt * 16 + t;
        rowc[t] = alist[b * kMaxPos + ((idx < cb) ? idx : (cb - 1))];
      }
      __syncthreads();
      {
        int r = t >> 4, part = t & 15;
        const float4* row4 = (const float4*)(f + (size_t)(b * kC + rowc[r]) * kD) + part * 12;
        float ss = 0.f;
        #pragma unroll
        for (int i = 0; i < 12; ++i) {
          float4 v = row4[i];
          ss += v.x * v.x + v.y * v.y + v.z * v.z + v.w * v.w;
        }
        #pragma unroll
        for (int off = 8; off > 0; off >>= 1) ss += __shfl_xor(ss, off, 16);
        if (part == 0) scl16[r] = 1.0f / fmaxf(sqrtf(ss), 1e-12f);
      }
      __syncthreads();
      #pragma unroll
      for (int i = 0; i < 6; ++i) {
        int chunk = i * 256 + t;
        int ks = chunk >> 6;
        int cl = chunk & 63;
        int rr = cl & 15;
        int k0 = ks * 32 + (cl >> 4) * 8;
        const float* src = f + (size_t)(b * kC + rowc[rr]) * kD + k0;  // L1/L2-warm
        float s = scl16[rr];
        float4 a = *(const float4*)(src);
        float4 b_ = *(const float4*)(src + 4);
        int4 pk;
        pk.x = bfr(a.x * s) | (bfr(a.y * s) << 16);
        pk.y = bfr(a.z * s) | (bfr(a.w * s) << 16);
        pk.z = bfr(b_.x * s) | (bfr(b_.y * s) << 16);
        pk.w = bfr(b_.z * s) | (bfr(b_.w * s) << 16);
        afrag[chunk] = pk;
      }
      __syncthreads();

      // K-loop: wave wq owns 4 N-tiles; depth-3 rotating register prefetch
      int gnt0 = nb * 16 + wq * 4;
      f32x4_t acc[4];
      #pragma unroll
      for (int nt = 0; nt < 4; ++nt) acc[nt] = (f32x4_t){0.f, 0.f, 0.f, 0.f};

      I4S8 a[3];
      I4S8 bb[3][4];
      size_t bofs[4];
      #pragma unroll
      for (int nt = 0; nt < 4; ++nt) bofs[nt] = ((size_t)(gnt0 + nt) * kKS) * 64 + ln;

      auto LOADK = [&](int ks, int s) {
        a[s].i = afrag[ks * 64 + ln];
        #pragma unroll
        for (int nt = 0; nt < 4; ++nt) bb[s][nt].i = pnf[bofs[nt] + (size_t)ks * 64];
      };
      LOADK(0, 0);
      LOADK(1, 1);
      #pragma unroll
      for (int ks = 0; ks < kKS; ++ks) {
        int s = ks % 3;
        int sn = (ks + 2) % 3;
        if (ks + 2 < kKS) LOADK(ks + 2, sn);
        #pragma unroll
        for (int nt = 0; nt < 4; ++nt)
          acc[nt] = __builtin_amdgcn_mfma_f32_16x16x32_bf16(a[s].s, bb[s][nt].s, acc[nt], 0, 0, 0);
      }

      // store tempered sims (C/D layout: col=ln&15, row=(ln>>4)*4+reg)
      float* srow = simsg + (size_t)(b * kMT + mt) * 16 * kC;
      #pragma unroll
      for (int nt = 0; nt < 4; ++nt) {
        int col = nb * 256 + wq * 64 + nt * 16 + (ln & 15);
        #pragma unroll
        for (int reg = 0; reg < 4; ++reg) {
          int rr = (ln >> 4) * 4 + reg;
          srow[rr * kC + col] = acc[nt][reg] * kTauInv;
        }
      }
    }
  }

  __threadfence();
  grid.sync();

  // ================= phase 3: epilogue, one anchor row per wave =================
  {
    int g = blk * 4 + wq;       // [0, 2048)
    int b = g >> 7;             // 128 waves per batch
    int ridx = g & 127;
    int cb = cnt[b];
    if (ridx < cb) {
      int c = alist[b * kMaxPos + ridx];
      int mt = ridx >> 4, rr = ridx & 15;
      const float* srow = simsg + ((size_t)(b * kMT + mt) * 16 + rr) * kC;
      const int* frow = flags + b * kC;

      int fl[16];
      #pragma unroll
      for (int j = 0; j < 16; ++j) fl[j] = frow[ln + 64 * j];

      float pos = srow[c];
      float v[16]; unsigned mk[16];
      float mx = -INFINITY;
      #pragma unroll
      for (int j = 0; j < 16; ++j) {
        float s = srow[ln + 64 * j];
        float m_ = (fl[j] & 2) ? -INFINITY : s;
        v[j] = m_; mk[j] = fkey(m_);
        mx = fmaxf(mx, m_);
      }
      #pragma unroll
      for (int off = 32; off > 0; off >>= 1) mx = fmaxf(mx, __shfl_xor(mx, off, 64));

      unsigned lo = 0u, hi = 0xFFFFFFFFu;
      while (lo < hi) {
        unsigned mid = lo + ((hi - lo) >> 1);
        int c_;
        BALLOT_COUNT16(mk[j] > mid, c_);
        if (c_ >= K_hard) lo = mid + 1u; else hi = mid;
      }
      unsigned thr = lo;

      int n_g, n_eq;
      BALLOT_COUNT16(mk[j] > thr, n_g);
      BALLOT_COUNT16(mk[j] == thr, n_eq);
      int need = K_hard - n_g;

      float ssum = 0.f;
      if (n_eq <= need) {
        #pragma unroll
        for (int j = 0; j < 16; ++j) {
          float ev = (v[j] == -INFINITY) ? 0.f : __expf(v[j] - mx);
          if (mk[j] >= thr) ssum += ev;
          if (fl[j] & 1) ssum += ev;
        }
      } else {
        int pref = 0;
        #pragma unroll
        for (int j = 0; j < 16; ++j) {
          unsigned long long ball = __ballot(mk[j] == thr);
          int rank = pref + __popcll(ball & ((1ull << ln) - 1ull));
          bool selh = (mk[j] > thr) || (mk[j] == thr && rank < need);
          float ev = (v[j] == -INFINITY) ? 0.f : __expf(v[j] - mx);
          if (selh) ssum += ev;
          if (fl[j] & 1) ssum += ev;
          pref += __popcll(ball);
        }
      }
      #pragma unroll
      for (int off = 32; off > 0; off >>= 1) ssum += __shfl_xor(ssum, off, 64);

      if (ln == 0) {
        float lse = mx + logf(ssum);
        float x = lse - pos;
        float pa = (x > 0.f) ? x + log1pf(__expf(-x)) : log1pf(__expf(x));
        atomicAdd(out, pa / (poscnt[b] * (float)B));
      }
    }
  }
}

extern "C" void kernel_launch(void* const* d_in, const int* in_sizes, int n_in,
                              void* d_out, int out_size, void* d_ws, size_t ws_size,
                              hipStream_t stream) {
  const float* f = (const float*)d_in[0];
  const float* proto = (const float*)d_in[1];
  const int* targets = (const int*)d_in[2];
  const float* rs = (const float*)d_in[3];

  const int D = in_sizes[0] / in_sizes[2];   // 768
  const int C = in_sizes[1] / D;             // 1024
  int B = in_sizes[2] / C;                   // 16
  const int K = C - 1;
  int K_hard = (int)(K * 0.3);               // 306
  int K_rand = K - K_hard;                   // 717

  // ws layout
  char* ws = (char*)d_ws;
  int* cnt = (int*)ws;                         // 16 ints       @ 0
  float* poscnt = (float*)(ws + 256);          // 16 floats     @ 256
  int* alist = (int*)(ws + 512);               // 16*128 ints   @ 512 (8 KB)
  int* flags = (int*)(ws + 16384);             // B*C ints      @ 16 KB (64 KB)
  int4* pnf = (int4*)(ws + 131072);            // C*D bf16      @ 128 KB (1.5 MB)
  float* sims = (float*)(ws + 2097152);        // 2048*1024 f32 @ 2 MB (8 MB)

  float* out = (float*)d_out;

  void* args[] = {(void*)&f, (void*)&proto, (void*)&targets, (void*)&rs,
                  (void*)&pnf, (void*)&flags, (void*)&cnt, (void*)&poscnt,
                  (void*)&alist, (void*)&sims, (void*)&out,
                  (void*)&B, (void*)&K_hard, (void*)&K_rand};
  hipLaunchCooperativeKernel((const void*)mono_kernel, dim3(512), dim3(kThreads),
                             args, 0, stream);
}

// Round 9
// 135.206 us; speedup vs baseline: 2.6492x; 2.6492x over previous
//
#include <hip/hip_runtime.h>
#include <cmath>

static constexpr int kC = 1024;
static constexpr int kD = 768;
static constexpr int kThreads = 256;
static constexpr float kTauInv = 10.0f;
static constexpr int kKS = kD / 32;        // 24 K-steps
static constexpr int kMaxPos = 128;        // per-batch anchor capacity (actual ~51)
static constexpr int kMT = kMaxPos / 16;   // 8 M-tiles per batch
static constexpr int kSS = 193;            // float4 stage stride per row (=772 floats)

typedef __attribute__((ext_vector_type(8))) short short8_t;
typedef __attribute__((ext_vector_type(4))) float f32x4_t;
union I4S8 { int4 i; short8_t s; };

__device__ __forceinline__ unsigned fkey(float f) {
  unsigned b = __float_as_uint(f);
  return (b & 0x80000000u) ? ~b : (b | 0x80000000u);
}
// inverse of fkey (valid for keys of real floats)
__device__ __forceinline__ float fkey_inv(unsigned k) {
  return __uint_as_float((k & 0x80000000u) ? (k ^ 0x80000000u) : ~k);
}

// round-to-nearest-even fp32 -> bf16 bits
__device__ __forceinline__ unsigned bfr(float x) {
  unsigned u = __float_as_uint(x);
  return (u + 0x7fffu + ((u >> 16) & 1u)) >> 16;
}

// wave-uniform count of a 16-element-per-lane predicate set via ballot+popcount
#define BALLOT_COUNT16(expr, dst)                       \
  {                                                     \
    int c__ = 0;                                        \
    _Pragma("unroll")                                   \
    for (int j = 0; j < 16; ++j)                        \
      c__ += (int)__popcll(__ballot(expr));             \
    dst = c__;                                          \
  }

// ---- K1 (fused prep): blocks 0..63 pack prototypes; blocks 64..79 rand-select per batch ----
__global__ void __launch_bounds__(kThreads) prep_kernel(
    const float* __restrict__ p, const int* __restrict__ targets,
    const float* __restrict__ rs, int4* __restrict__ pnf,
    int* __restrict__ flags, int* __restrict__ cnt, float* __restrict__ poscnt,
    int* __restrict__ alist, float* __restrict__ out, int K_rand) {
  __shared__ float4 pstage[16 * kSS];
  __shared__ float scl[16];
  __shared__ unsigned keys[kC];
  int t = threadIdx.x;
  if (blockIdx.x == 0 && t == 0) *out = 0.f;

  if (blockIdx.x < 64) {
    int n0 = blockIdx.x * 16;
    const float4* psrc = (const float4*)p + (size_t)n0 * (kD / 4);
    #pragma unroll
    for (int i = 0; i < 12; ++i) {
      int j = t + 256 * i;
      int r = j / 192, o = j % 192;
      pstage[r * kSS + o] = psrc[j];
    }
    __syncthreads();
    {
      int r = t >> 4, part = t & 15;
      float ss = 0.f;
      #pragma unroll
      for (int i = 0; i < 12; ++i) {
        float4 v = pstage[r * kSS + part * 12 + i];
        ss += v.x * v.x + v.y * v.y + v.z * v.z + v.w * v.w;
      }
      #pragma unroll
      for (int off = 8; off > 0; off >>= 1) ss += __shfl_xor(ss, off, 16);
      if (part == 0) scl[r] = 1.0f / fmaxf(sqrtf(ss), 1e-12f);
    }
    __syncthreads();
    const float* pst = (const float*)pstage;
    #pragma unroll
    for (int i = 0; i < 6; ++i) {
      int chunk = i * 256 + t;
      int ks = chunk >> 6;
      int ln = chunk & 63;
      int col = ln & 15;
      int k0 = ks * 32 + (ln >> 4) * 8;
      const float* src = pst + col * (kSS * 4) + k0;
      float s = scl[col];
      float4 a = *(const float4*)(src);
      float4 b = *(const float4*)(src + 4);
      int4 pk;
      pk.x = bfr(a.x * s) | (bfr(a.y * s) << 16);
      pk.y = bfr(a.z * s) | (bfr(a.w * s) << 16);
      pk.z = bfr(b.x * s) | (bfr(b.y * s) << 16);
      pk.w = bfr(b.z * s) | (bfr(b.w * s) << 16);
      pnf[(size_t)((blockIdx.x * kKS + ks) << 6) + ln] = pk;
    }
  } else {
    int b = blockIdx.x - 64;
    int wq = t >> 6, ln = t & 63;
    #pragma unroll
    for (int k = 0; k < 4; ++k) {
      int e = t + 256 * k;
      int tg = targets[b * kC + e];
      float v = (tg == 0) ? rs[b * kC + e] : -INFINITY;
      keys[e] = fkey(v);  // positives -> fkey(-inf) < 0x80000000 <= fkey(rs>=0)
    }
    __syncthreads();
    unsigned mk[16];
    #pragma unroll
    for (int j = 0; j < 16; ++j) mk[j] = keys[ln + 64 * j];

    unsigned lo = 0u, hi = 0xFFFFFFFFu;
    while (lo < hi) {
      unsigned mid = lo + ((hi - lo) >> 1);
      int c_;
      BALLOT_COUNT16(mk[j] > mid, c_);
      if (c_ >= K_rand) lo = mid + 1u; else hi = mid;
    }
    unsigned thr = lo;

    int n_g, n_eq, cp;
    BALLOT_COUNT16(mk[j] > thr, n_g);
    BALLOT_COUNT16(mk[j] == thr, n_eq);
    BALLOT_COUNT16(mk[j] < 0x80000000u, cp);
    int need = K_rand - n_g;
    bool take_all_eq = (n_eq <= need);

    if (t == 0) {
      poscnt[b] = fmaxf((float)cp, 1.f);
      cnt[b] = (cp < kMaxPos) ? cp : kMaxPos;
    }

    if (wq == 0) {
      int pref = 0;
      #pragma unroll
      for (int j = 0; j < 16; ++j) {
        unsigned long long ball = __ballot(mk[j] < 0x80000000u);
        if (mk[j] < 0x80000000u) {
          int rank = pref + __popcll(ball & ((1ull << ln) - 1ull));
          if (rank < kMaxPos) alist[b * kMaxPos + rank] = ln + 64 * j;
        }
        pref += __popcll(ball);
      }
    }

    if (take_all_eq) {
      #pragma unroll
      for (int k = 0; k < 4; ++k) {
        int j = wq + 4 * k;
        int e = ln + 64 * j;  // == t + 256*k
        unsigned kk = mk[j];
        int sel = (kk >= thr && kk >= 0x80000000u) ? 1 : 0;
        int pos = (kk < 0x80000000u) ? 2 : 0;
        flags[b * kC + e] = sel | pos;
      }
    } else {
      int pref = 0;
      int rankj[16];
      #pragma unroll
      for (int j = 0; j < 16; ++j) {
        unsigned long long ball = __ballot(mk[j] == thr);
        rankj[j] = pref + __popcll(ball & ((1ull << ln) - 1ull));
        pref += __popcll(ball);
      }
      #pragma unroll
      for (int k = 0; k < 4; ++k) {
        int j = wq + 4 * k;
        int e = ln + 64 * j;
        unsigned kk = mk[j];
        int sel = (kk > thr) ? 1 : ((kk == thr && rankj[j] < need) ? 1 : 0);
        int pos = (kk < 0x80000000u) ? 2 : 0;
        flags[b * kC + e] = sel | pos;
      }
    }
  }
}

// ---- K2: GEMM. grid = 16 b x 8 mt x 4 nb; block = 16 rows x 256 cols x K=768 ----
__global__ void __launch_bounds__(kThreads) gemm_kernel(
    const float* __restrict__ f, const int4* __restrict__ pnf,
    const int* __restrict__ alist, const int* __restrict__ cnt,
    float* __restrict__ simsg) {
  __shared__ float4 fstage[16 * kSS];
  __shared__ __align__(16) int4 afrag[kKS * 64];
  __shared__ int rowc[16];
  __shared__ float rowscl[16];

  int bidx = blockIdx.x;
  int b = bidx >> 5;
  int mt = (bidx >> 2) & 7;
  int nb = bidx & 3;
  int cb = cnt[b];
  if (mt * 16 >= cb) return;
  int t = threadIdx.x;

  if (t < 16) {
    int idx = mt * 16 + t;
    rowc[t] = alist[b * kMaxPos + ((idx < cb) ? idx : (cb - 1))];
  }
  __syncthreads();

  #pragma unroll
  for (int i = 0; i < 12; ++i) {
    int j = t + 256 * i;
    int r = j / 192, o = j % 192;
    fstage[r * kSS + o] = ((const float4*)f)[(size_t)(b * kC + rowc[r]) * (kD / 4) + o];
  }
  __syncthreads();
  {
    int r = t >> 4, part = t & 15;
    float ss = 0.f;
    #pragma unroll
    for (int i = 0; i < 12; ++i) {
      float4 v = fstage[r * kSS + part * 12 + i];
      ss += v.x * v.x + v.y * v.y + v.z * v.z + v.w * v.w;
    }
    #pragma unroll
    for (int off = 8; off > 0; off >>= 1) ss += __shfl_xor(ss, off, 16);
    if (part == 0) rowscl[r] = 1.0f / fmaxf(sqrtf(ss), 1e-12f);
  }
  __syncthreads();
  {
    const float* fst = (const float*)fstage;
    #pragma unroll
    for (int i = 0; i < 6; ++i) {
      int chunk = i * 256 + t;
      int ks = chunk >> 6;
      int ln = chunk & 63;
      int rr = ln & 15;
      int k0 = ks * 32 + (ln >> 4) * 8;
      const float* src = fst + rr * (kSS * 4) + k0;
      float s = rowscl[rr];
      float4 a = *(const float4*)(src);
      float4 b_ = *(const float4*)(src + 4);
      int4 pk;
      pk.x = bfr(a.x * s) | (bfr(a.y * s) << 16);
      pk.y = bfr(a.z * s) | (bfr(a.w * s) << 16);
      pk.z = bfr(b_.x * s) | (bfr(b_.y * s) << 16);
      pk.w = bfr(b_.z * s) | (bfr(b_.w * s) << 16);
      afrag[chunk] = pk;
    }
  }
  __syncthreads();

  int wq = t >> 6, ln = t & 63;
  int gnt0 = nb * 16 + wq * 4;
  f32x4_t acc[4];
  #pragma unroll
  for (int nt = 0; nt < 4; ++nt) acc[nt] = (f32x4_t){0.f, 0.f, 0.f, 0.f};

  I4S8 a[3];
  I4S8 bb[3][4];
  size_t bofs[4];
  #pragma unroll
  for (int nt = 0; nt < 4; ++nt) bofs[nt] = ((size_t)(gnt0 + nt) * kKS) * 64 + ln;

  auto LOADK = [&](int ks, int s) {
    a[s].i = afrag[ks * 64 + ln];
    #pragma unroll
    for (int nt = 0; nt < 4; ++nt) bb[s][nt].i = pnf[bofs[nt] + (size_t)ks * 64];
  };
  LOADK(0, 0);
  LOADK(1, 1);
  #pragma unroll
  for (int ks = 0; ks < kKS; ++ks) {
    int s = ks % 3;
    int sn = (ks + 2) % 3;
    if (ks + 2 < kKS) LOADK(ks + 2, sn);
    #pragma unroll
    for (int nt = 0; nt < 4; ++nt)
      acc[nt] = __builtin_amdgcn_mfma_f32_16x16x32_bf16(a[s].s, bb[s][nt].s, acc[nt], 0, 0, 0);
  }

  float* srow = simsg + (size_t)(b * kMT + mt) * 16 * kC;
  #pragma unroll
  for (int nt = 0; nt < 4; ++nt) {
    int col = nb * 256 + wq * 64 + nt * 16 + (ln & 15);
    #pragma unroll
    for (int reg = 0; reg < 4; ++reg) {
      int rr = (ln >> 4) * 4 + reg;
      srow[rr * kC + col] = acc[nt][reg] * kTauInv;
    }
  }
}

// ---- K3: epilogue, slim-register version. grid = 16 b x 32 groups; 1 row/wave ----
// Live set: mk[16] + rbits + scalars (~28 VGPR) -- no v[16]/fl[16] arrays, no spill.
__global__ void __launch_bounds__(kThreads) epi_kernel(
    const float* __restrict__ simsg, const int* __restrict__ flags,
    const int* __restrict__ alist, const int* __restrict__ cnt,
    const float* __restrict__ poscnt, float* __restrict__ out,
    int B, int K_hard) {
  int b = blockIdx.x >> 5;
  int g4 = blockIdx.x & 31;
  int cb = cnt[b];
  if (g4 * 4 >= cb) return;
  int t = threadIdx.x;
  int wq = t >> 6, ln = t & 63;

  int ridx = g4 * 4 + wq;
  if (ridx >= cb) return;
  int mt = ridx >> 4;
  int rr = ridx & 15;
  int c = alist[b * kMaxPos + ridx];
  const float* srow = simsg + ((size_t)(b * kMT + mt) * 16 + rr) * kC;
  const int* frow = flags + b * kC;

  float pos = srow[c];

  unsigned mk[16];
  unsigned rbits = 0;
  #pragma unroll
  for (int j = 0; j < 16; ++j) {
    float s = srow[ln + 64 * j];
    int fl = frow[ln + 64 * j];
    mk[j] = (fl & 2) ? 0u : fkey(s);   // positives -> key 0 (below every real key)
    rbits |= (unsigned)(fl & 1) << j;  // rand-selected (never a positive)
  }

  // row max in key space (order-preserving)
  unsigned mxk = 0u;
  #pragma unroll
  for (int j = 0; j < 16; ++j) mxk = mk[j] > mxk ? mk[j] : mxk;
  #pragma unroll
  for (int off = 32; off > 0; off >>= 1) {
    unsigned o = __shfl_xor((int)mxk, off, 64);
    mxk = o > mxk ? o : mxk;
  }
  float mx = fkey_inv(mxk);

  // binary search for K_hard-th largest key; |sims|<=10.0001 -> seed [-11,11]
  unsigned lo = fkey(-11.0f), hi = fkey(11.0f);
  while (lo < hi) {
    unsigned mid = lo + ((hi - lo) >> 1);
    int c_;
    BALLOT_COUNT16(mk[j] > mid, c_);
    if (c_ >= K_hard) lo = mid + 1u; else hi = mid;
  }
  unsigned thr = lo;

  int n_g, n_eq;
  BALLOT_COUNT16(mk[j] > thr, n_g);
  BALLOT_COUNT16(mk[j] == thr, n_eq);
  int need = K_hard - n_g;

  float ssum = 0.f;
  if (n_eq <= need) {
    #pragma unroll
    for (int j = 0; j < 16; ++j) {
      float ev = (mk[j] == 0u) ? 0.f : __expf(fkey_inv(mk[j]) - mx);
      if (mk[j] >= thr) ssum += ev;
      if ((rbits >> j) & 1) ssum += ev;
    }
  } else {  // rare tie path: lowest-index-first among == thr
    int pref = 0;
    #pragma unroll
    for (int j = 0; j < 16; ++j) {
      unsigned long long ball = __ballot(mk[j] == thr);
      int rank = pref + __popcll(ball & ((1ull << ln) - 1ull));
      bool selh = (mk[j] > thr) || (mk[j] == thr && rank < need);
      float ev = (mk[j] == 0u) ? 0.f : __expf(fkey_inv(mk[j]) - mx);
      if (selh) ssum += ev;
      if ((rbits >> j) & 1) ssum += ev;
      pref += __popcll(ball);
    }
  }
  #pragma unroll
  for (int off = 32; off > 0; off >>= 1) ssum += __shfl_xor(ssum, off, 64);

  if (ln == 0) {
    float lse = mx + logf(ssum);
    float x = lse - pos;
    float pa = (x > 0.f) ? x + log1pf(__expf(-x)) : log1pf(__expf(x));
    atomicAdd(out, pa / (poscnt[b] * (float)B));
  }
}

extern "C" void kernel_launch(void* const* d_in, const int* in_sizes, int n_in,
                              void* d_out, int out_size, void* d_ws, size_t ws_size,
                              hipStream_t stream) {
  const float* f = (const float*)d_in[0];
  const float* proto = (const float*)d_in[1];
  const int* targets = (const int*)d_in[2];
  const float* rs = (const float*)d_in[3];

  const int D = in_sizes[0] / in_sizes[2];   // 768
  const int C = in_sizes[1] / D;             // 1024
  const int B = in_sizes[2] / C;             // 16
  const int K = C - 1;
  const int K_hard = (int)(K * 0.3);         // 306
  const int K_rand = K - K_hard;             // 717

  // ws layout
  char* ws = (char*)d_ws;
  int* cnt = (int*)ws;                         // 16 ints       @ 0
  float* poscnt = (float*)(ws + 256);          // 16 floats     @ 256
  int* alist = (int*)(ws + 512);               // 16*128 ints   @ 512 (8 KB)
  int* flags = (int*)(ws + 16384);             // B*C ints      @ 16 KB (64 KB)
  int4* pnf = (int4*)(ws + 131072);            // C*D bf16      @ 128 KB (1.5 MB)
  float* sims = (float*)(ws + 2097152);        // 2048*1024 f32 @ 2 MB (8 MB)

  float* out = (float*)d_out;

  prep_kernel<<<80, kThreads, 0, stream>>>(proto, targets, rs, pnf, flags, cnt, poscnt, alist, out, K_rand);
  gemm_kernel<<<16 * 8 * 4, kThreads, 0, stream>>>(f, pnf, alist, cnt, sims);
  epi_kernel<<<16 * 32, kThreads, 0, stream>>>(sims, flags, alist, cnt, poscnt, out, B, K_hard);
}

// Round 10
// 130.361 us; speedup vs baseline: 2.7476x; 1.0372x over previous
//
#include <hip/hip_runtime.h>
#include <cmath>

static constexpr int kC = 1024;
static constexpr int kD = 768;
static constexpr int kThreads = 256;
static constexpr float kTauInv = 10.0f;
static constexpr int kKS = kD / 32;        // 24 K-steps
static constexpr int kMaxPos = 128;        // per-batch anchor capacity (actual ~51)
static constexpr int kMT = kMaxPos / 16;   // 8 M-tiles per batch
static constexpr int kSS = 193;            // float4 stage stride per row (=772 floats; 2-way max LDS conflict)

typedef __attribute__((ext_vector_type(8))) short short8_t;
typedef __attribute__((ext_vector_type(4))) float f32x4_t;
union I4S8 { int4 i; short8_t s; };

__device__ __forceinline__ unsigned fkey(float f) {
  unsigned b = __float_as_uint(f);
  return (b & 0x80000000u) ? ~b : (b | 0x80000000u);
}

// round-to-nearest-even fp32 -> bf16 bits
__device__ __forceinline__ unsigned bfr(float x) {
  unsigned u = __float_as_uint(x);
  return (u + 0x7fffu + ((u >> 16) & 1u)) >> 16;
}

// wave-uniform count of a 16-element-per-lane predicate set via ballot+popcount
// (VALU v_cmp + scalar s_bcnt1 -- no DS-pipe shuffles)
#define BALLOT_COUNT16(expr, dst)                       \
  {                                                     \
    int c__ = 0;                                        \
    _Pragma("unroll")                                   \
    for (int j = 0; j < 16; ++j)                        \
      c__ += (int)__popcll(__ballot(expr));             \
    dst = c__;                                          \
  }

// ---- K1 (fused prep): blocks 0..63 pack prototypes; blocks 64..79 rand-select per batch ----
// pnf layout (int4 units): index = (gnt*kKS + ks)*64 + ln
//   holds pn[col = gnt*16 + (ln&15)][k = ks*32 + (ln>>4)*8 .. +8]
__global__ void __launch_bounds__(kThreads) prep_kernel(
    const float* __restrict__ p, const int* __restrict__ targets,
    const float* __restrict__ rs, int4* __restrict__ pnf,
    int* __restrict__ flags, int* __restrict__ cnt, float* __restrict__ poscnt,
    int* __restrict__ alist, float* __restrict__ out, int K_rand) {
  __shared__ float4 pstage[16 * kSS];
  __shared__ float scl[16];
  __shared__ unsigned keys[kC];
  int t = threadIdx.x;
  if (blockIdx.x == 0 && t == 0) *out = 0.f;

  if (blockIdx.x < 64) {
    int n0 = blockIdx.x * 16;
    const float4* psrc = (const float4*)p + (size_t)n0 * (kD / 4);
    #pragma unroll
    for (int i = 0; i < 12; ++i) {
      int j = t + 256 * i;
      int r = j / 192, o = j % 192;
      pstage[r * kSS + o] = psrc[j];
    }
    __syncthreads();
    {
      int r = t >> 4, part = t & 15;
      float ss = 0.f;
      #pragma unroll
      for (int i = 0; i < 12; ++i) {
        float4 v = pstage[r * kSS + part * 12 + i];
        ss += v.x * v.x + v.y * v.y + v.z * v.z + v.w * v.w;
      }
      #pragma unroll
      for (int off = 8; off > 0; off >>= 1) ss += __shfl_xor(ss, off, 16);
      if (part == 0) scl[r] = 1.0f / fmaxf(sqrtf(ss), 1e-12f);
    }
    __syncthreads();
    const float* pst = (const float*)pstage;
    #pragma unroll
    for (int i = 0; i < 6; ++i) {
      int chunk = i * 256 + t;
      int ks = chunk >> 6;
      int ln = chunk & 63;
      int col = ln & 15;
      int k0 = ks * 32 + (ln >> 4) * 8;
      const float* src = pst + col * (kSS * 4) + k0;
      float s = scl[col];
      float4 a = *(const float4*)(src);
      float4 b = *(const float4*)(src + 4);
      int4 pk;
      pk.x = bfr(a.x * s) | (bfr(a.y * s) << 16);
      pk.y = bfr(a.z * s) | (bfr(a.w * s) << 16);
      pk.z = bfr(b.x * s) | (bfr(b.y * s) << 16);
      pk.w = bfr(b.z * s) | (bfr(b.w * s) << 16);
      pnf[(size_t)((blockIdx.x * kKS + ks) << 6) + ln] = pk;
    }
  } else {
    int b = blockIdx.x - 64;
    int wq = t >> 6, ln = t & 63;
    #pragma unroll
    for (int k = 0; k < 4; ++k) {
      int e = t + 256 * k;
      int tg = targets[b * kC + e];
      float v = (tg == 0) ? rs[b * kC + e] : -INFINITY;
      keys[e] = fkey(v);  // positives -> fkey(-inf) < 0x80000000 <= fkey(rs>=0)
    }
    __syncthreads();
    unsigned mk[16];
    #pragma unroll
    for (int j = 0; j < 16; ++j) mk[j] = keys[ln + 64 * j];

    unsigned lo = 0u, hi = 0xFFFFFFFFu;
    while (lo < hi) {
      unsigned mid = lo + ((hi - lo) >> 1);
      int c_;
      BALLOT_COUNT16(mk[j] > mid, c_);
      if (c_ >= K_rand) lo = mid + 1u; else hi = mid;
    }
    unsigned thr = lo;

    int n_g, n_eq, cp;
    BALLOT_COUNT16(mk[j] > thr, n_g);
    BALLOT_COUNT16(mk[j] == thr, n_eq);
    BALLOT_COUNT16(mk[j] < 0x80000000u, cp);
    int need = K_rand - n_g;
    bool take_all_eq = (n_eq <= need);

    if (t == 0) {
      poscnt[b] = fmaxf((float)cp, 1.f);
      cnt[b] = (cp < kMaxPos) ? cp : kMaxPos;
    }

    if (wq == 0) {
      int pref = 0;
      #pragma unroll
      for (int j = 0; j < 16; ++j) {
        unsigned long long ball = __ballot(mk[j] < 0x80000000u);
        if (mk[j] < 0x80000000u) {
          int rank = pref + __popcll(ball & ((1ull << ln) - 1ull));
          if (rank < kMaxPos) alist[b * kMaxPos + rank] = ln + 64 * j;
        }
        pref += __popcll(ball);
      }
    }

    if (take_all_eq) {
      #pragma unroll
      for (int k = 0; k < 4; ++k) {
        int j = wq + 4 * k;
        int e = ln + 64 * j;  // == t + 256*k
        unsigned kk = mk[j];
        int sel = (kk >= thr && kk >= 0x80000000u) ? 1 : 0;
        int pos = (kk < 0x80000000u) ? 2 : 0;
        flags[b * kC + e] = sel | pos;
      }
    } else {
      int pref = 0;
      int rankj[16];
      #pragma unroll
      for (int j = 0; j < 16; ++j) {
        unsigned long long ball = __ballot(mk[j] == thr);
        rankj[j] = pref + __popcll(ball & ((1ull << ln) - 1ull));
        pref += __popcll(ball);
      }
      #pragma unroll
      for (int k = 0; k < 4; ++k) {
        int j = wq + 4 * k;
        int e = ln + 64 * j;
        unsigned kk = mk[j];
        int sel = (kk > thr) ? 1 : ((kk == thr && rankj[j] < need) ? 1 : 0);
        int pos = (kk < 0x80000000u) ? 2 : 0;
        flags[b * kC + e] = sel | pos;
      }
    }
  }
}

// ---- K2: GEMM. grid = 16 b x 8 mt x 4 nb; block = 16 rows x 256 cols x K=768 ----
__global__ void __launch_bounds__(kThreads) gemm_kernel(
    const float* __restrict__ f, const int4* __restrict__ pnf,
    const int* __restrict__ alist, const int* __restrict__ cnt,
    float* __restrict__ simsg) {
  __shared__ float4 fstage[16 * kSS];
  __shared__ __align__(16) int4 afrag[kKS * 64];
  __shared__ int rowc[16];
  __shared__ float rowscl[16];

  int bidx = blockIdx.x;
  int b = bidx >> 5;
  int mt = (bidx >> 2) & 7;
  int nb = bidx & 3;
  int cb = cnt[b];
  if (mt * 16 >= cb) return;
  int t = threadIdx.x;

  if (t < 16) {
    int idx = mt * 16 + t;
    rowc[t] = alist[b * kMaxPos + ((idx < cb) ? idx : (cb - 1))];
  }
  __syncthreads();

  // stage the 16 f rows (coalesced) into LDS
  #pragma unroll
  for (int i = 0; i < 12; ++i) {
    int j = t + 256 * i;
    int r = j / 192, o = j % 192;
    fstage[r * kSS + o] = ((const float4*)f)[(size_t)(b * kC + rowc[r]) * (kD / 4) + o];
  }
  __syncthreads();
  {
    int r = t >> 4, part = t & 15;
    float ss = 0.f;
    #pragma unroll
    for (int i = 0; i < 12; ++i) {
      float4 v = fstage[r * kSS + part * 12 + i];
      ss += v.x * v.x + v.y * v.y + v.z * v.z + v.w * v.w;
    }
    #pragma unroll
    for (int off = 8; off > 0; off >>= 1) ss += __shfl_xor(ss, off, 16);
    if (part == 0) rowscl[r] = 1.0f / fmaxf(sqrtf(ss), 1e-12f);
  }
  __syncthreads();
  {
    const float* fst = (const float*)fstage;
    #pragma unroll
    for (int i = 0; i < 6; ++i) {
      int chunk = i * 256 + t;
      int ks = chunk >> 6;
      int ln = chunk & 63;
      int rr = ln & 15;
      int k0 = ks * 32 + (ln >> 4) * 8;
      const float* src = fst + rr * (kSS * 4) + k0;
      float s = rowscl[rr];
      float4 a = *(const float4*)(src);
      float4 b_ = *(const float4*)(src + 4);
      int4 pk;
      pk.x = bfr(a.x * s) | (bfr(a.y * s) << 16);
      pk.y = bfr(a.z * s) | (bfr(a.w * s) << 16);
      pk.z = bfr(b_.x * s) | (bfr(b_.y * s) << 16);
      pk.w = bfr(b_.z * s) | (bfr(b_.w * s) << 16);
      afrag[chunk] = pk;
    }
  }
  __syncthreads();

  // K-loop: wave wq owns 4 N-tiles (64 cols); depth-3 rotating register prefetch
  int wq = t >> 6, ln = t & 63;
  int gnt0 = nb * 16 + wq * 4;
  f32x4_t acc[4];
  #pragma unroll
  for (int nt = 0; nt < 4; ++nt) acc[nt] = (f32x4_t){0.f, 0.f, 0.f, 0.f};

  I4S8 a[3];
  I4S8 bb[3][4];
  size_t bofs[4];
  #pragma unroll
  for (int nt = 0; nt < 4; ++nt) bofs[nt] = ((size_t)(gnt0 + nt) * kKS) * 64 + ln;

  auto LOADK = [&](int ks, int s) {
    a[s].i = afrag[ks * 64 + ln];
    #pragma unroll
    for (int nt = 0; nt < 4; ++nt) bb[s][nt].i = pnf[bofs[nt] + (size_t)ks * 64];
  };
  LOADK(0, 0);
  LOADK(1, 1);
  #pragma unroll
  for (int ks = 0; ks < kKS; ++ks) {
    int s = ks % 3;
    int sn = (ks + 2) % 3;
    if (ks + 2 < kKS) LOADK(ks + 2, sn);
    #pragma unroll
    for (int nt = 0; nt < 4; ++nt)
      acc[nt] = __builtin_amdgcn_mfma_f32_16x16x32_bf16(a[s].s, bb[s][nt].s, acc[nt], 0, 0, 0);
  }

  // store tempered sims (C/D layout: col=ln&15, row=(ln>>4)*4+reg)
  float* srow = simsg + (size_t)(b * kMT + mt) * 16 * kC;
  #pragma unroll
  for (int nt = 0; nt < 4; ++nt) {
    int col = nb * 256 + wq * 64 + nt * 16 + (ln & 15);
    #pragma unroll
    for (int reg = 0; reg < 4; ++reg) {
      int rr = (ln >> 4) * 4 + reg;
      srow[rr * kC + col] = acc[nt][reg] * kTauInv;
    }
  }
}

// ---- K3: epilogue. grid = 16 b x 32 groups; ONE anchor row per wave ----
__global__ void __launch_bounds__(kThreads) epi_kernel(
    const float* __restrict__ simsg, const int* __restrict__ flags,
    const int* __restrict__ alist, const int* __restrict__ cnt,
    const float* __restrict__ poscnt, float* __restrict__ out,
    int B, int K_hard) {
  int b = blockIdx.x >> 5;
  int g4 = blockIdx.x & 31;           // group of 4 rows
  int cb = cnt[b];
  if (g4 * 4 >= cb) return;
  int t = threadIdx.x;
  int wq = t >> 6, ln = t & 63;

  int ridx = g4 * 4 + wq;             // this wave's anchor row
  if (ridx >= cb) return;
  int mt = ridx >> 4;
  int rr = ridx & 15;
  int c = alist[b * kMaxPos + ridx];
  const float* srow = simsg + ((size_t)(b * kMT + mt) * 16 + rr) * kC;
  const int* frow = flags + b * kC;

  int fl[16];
  #pragma unroll
  for (int j = 0; j < 16; ++j) fl[j] = frow[ln + 64 * j];

  float pos = srow[c];
  float v[16]; unsigned mk[16];
  float mx = -INFINITY;
  #pragma unroll
  for (int j = 0; j < 16; ++j) {
    float s = srow[ln + 64 * j];
    float m_ = (fl[j] & 2) ? -INFINITY : s;
    v[j] = m_; mk[j] = fkey(m_);
    mx = fmaxf(mx, m_);
  }
  #pragma unroll
  for (int off = 32; off > 0; off >>= 1) mx = fmaxf(mx, __shfl_xor(mx, off, 64));

  // ballot-based binary search for K_hard-th largest key (no DS-pipe in the loop)
  unsigned lo = 0u, hi = 0xFFFFFFFFu;
  while (lo < hi) {
    unsigned mid = lo + ((hi - lo) >> 1);
    int c_;
    BALLOT_COUNT16(mk[j] > mid, c_);
    if (c_ >= K_hard) lo = mid + 1u; else hi = mid;
  }
  unsigned thr = lo;

  int n_g, n_eq;
  BALLOT_COUNT16(mk[j] > thr, n_g);
  BALLOT_COUNT16(mk[j] == thr, n_eq);
  int need = K_hard - n_g;

  float ssum = 0.f;
  if (n_eq <= need) {
    #pragma unroll
    for (int j = 0; j < 16; ++j) {
      float ev = (v[j] == -INFINITY) ? 0.f : __expf(v[j] - mx);
      if (mk[j] >= thr) ssum += ev;
      if (fl[j] & 1) ssum += ev;
    }
  } else {
    int pref = 0;
    #pragma unroll
    for (int j = 0; j < 16; ++j) {
      unsigned long long ball = __ballot(mk[j] == thr);
      int rank = pref + __popcll(ball & ((1ull << ln) - 1ull));
      bool selh = (mk[j] > thr) || (mk[j] == thr && rank < need);
      float ev = (v[j] == -INFINITY) ? 0.f : __expf(v[j] - mx);
      if (selh) ssum += ev;
      if (fl[j] & 1) ssum += ev;
      pref += __popcll(ball);
    }
  }
  #pragma unroll
  for (int off = 32; off > 0; off >>= 1) ssum += __shfl_xor(ssum, off, 64);

  if (ln == 0) {
    float lse = mx + logf(ssum);
    float x = lse - pos;
    float pa = (x > 0.f) ? x + log1pf(__expf(-x)) : log1pf(__expf(x));
    atomicAdd(out, pa / (poscnt[b] * (float)B));
  }
}

extern "C" void kernel_launch(void* const* d_in, const int* in_sizes, int n_in,
                              void* d_out, int out_size, void* d_ws, size_t ws_size,
                              hipStream_t stream) {
  const float* f = (const float*)d_in[0];
  const float* proto = (const float*)d_in[1];
  const int* targets = (const int*)d_in[2];
  const float* rs = (const float*)d_in[3];

  const int D = in_sizes[0] / in_sizes[2];   // 768
  const int C = in_sizes[1] / D;             // 1024
  const int B = in_sizes[2] / C;             // 16
  const int K = C - 1;
  const int K_hard = (int)(K * 0.3);         // 306
  const int K_rand = K - K_hard;             // 717

  // ws layout (10 MB total)
  char* ws = (char*)d_ws;
  int* cnt = (int*)ws;                         // 16 ints       @ 0
  float* poscnt = (float*)(ws + 256);          // 16 floats     @ 256
  int* alist = (int*)(ws + 512);               // 16*128 ints   @ 512 (8 KB)
  int* flags = (int*)(ws + 16384);             // B*C ints      @ 16 KB (64 KB)
  int4* pnf = (int4*)(ws + 131072);            // C*D bf16      @ 128 KB (1.5 MB)
  float* sims = (float*)(ws + 2097152);        // 2048*1024 f32 @ 2 MB (8 MB)

  float* out = (float*)d_out;

  prep_kernel<<<80, kThreads, 0, stream>>>(proto, targets, rs, pnf, flags, cnt, poscnt, alist, out, K_rand);
  gemm_kernel<<<16 * 8 * 4, kThreads, 0, stream>>>(f, pnf, alist, cnt, sims);
  epi_kernel<<<16 * 32, kThreads, 0, stream>>>(sims, flags, alist, cnt, poscnt, out, B, K_hard);
}